// Round 9
// baseline (253.571 us; speedup 1.0000x reference)
//
#include <hip/hip_runtime.h>
#include <hip/hip_bf16.h>
#include <hip/hip_fp16.h>

// SGC: out = (D^-1/2 A D^-1/2)^2 x W + b.
// R8: gather fragment reshaped to one dwordx4 per edge per lane (6 active
// lanes x 16 B = 96 B row) instead of 3x dword (8 lanes x 12 B). 3x fewer
// vmem instructions on the latency-critical path. Unroll back to x4.
// CSR build + fused fine_sort (R7) unchanged.

#define N_NODES 100000
#define N_EDGES 1600000
#define IN_CH 48
#define OUT_CH 64
#define ROW 24                   // half2 per feature row (48 ch)
#define NBUCKETS 392             // bucket = col >> 8 (256 nodes each)
#define EPB 8192                 // edges per scatter block
#define NBLK_EDGE 196            // ceil(1.6M / 8192)
#define NBLK_BKT 391             // buckets containing real nodes

// ---- Pass A1: coarse bucket histogram (LDS-privatized) ----
__global__ void bucket_hist_kernel(const int* __restrict__ col, int* __restrict__ bucketCount) {
    __shared__ int lh[NBUCKETS];
    for (int i = threadIdx.x; i < NBUCKETS; i += 256) lh[i] = 0;
    __syncthreads();
    int base = blockIdx.x * EPB;
    #pragma unroll 4
    for (int k = 0; k < 32; k++) {
        int e = base + k * 256 + threadIdx.x;
        if (e < N_EDGES) atomicAdd(&lh[col[e] >> 8], 1);
    }
    __syncthreads();
    for (int i = threadIdx.x; i < NBUCKETS; i += 256)
        if (lh[i]) atomicAdd(&bucketCount[i], lh[i]);
}

// ---- Pass A2: exclusive scan of bucket counts ----
__global__ void bucket_scan_kernel(const int* __restrict__ bucketCount,
                                   int* __restrict__ bucketStart,
                                   int* __restrict__ bucketCursor) {
    __shared__ int l[NBUCKETS + 1];
    for (int i = threadIdx.x; i < NBUCKETS; i += 256) l[i] = bucketCount[i];
    __syncthreads();
    if (threadIdx.x == 0) {
        int t = 0;
        for (int k = 0; k < NBUCKETS; k++) { int c = l[k]; l[k] = t; t += c; }
        l[NBUCKETS] = t;
    }
    __syncthreads();
    for (int i = threadIdx.x; i <= NBUCKETS; i += 256) {
        bucketStart[i] = l[i];
        if (i < NBUCKETS) bucketCursor[i] = l[i];
    }
}

// ---- Pass A3: LDS-staged scatter of packed edges into bucket regions ----
__global__ void bucket_scatter_kernel(const int* __restrict__ row, const int* __restrict__ col,
                                      int* __restrict__ bucketCursor, int* __restrict__ bucketed) {
    __shared__ int lh[NBUCKETS];
    __shared__ int lofs[NBUCKETS];
    __shared__ int lbase[NBUCKETS];
    __shared__ int stage[EPB];
    __shared__ unsigned short sbkt[EPB];
    __shared__ int wsum[4];
    int tid = threadIdx.x;
    int base = blockIdx.x * EPB;
    for (int i = tid; i < NBUCKETS; i += 256) lh[i] = 0;
    __syncthreads();
    #pragma unroll 4
    for (int k = 0; k < 32; k++) {
        int e = base + k * 256 + tid;
        if (e < N_EDGES) atomicAdd(&lh[col[e] >> 8], 1);
    }
    __syncthreads();
    {
        int c0 = (tid < 196) ? lh[2 * tid] : 0;
        int c1 = (tid < 196) ? lh[2 * tid + 1] : 0;
        int s = c0 + c1;
        int incl = s;
        int lane = tid & 63, w = tid >> 6;
        #pragma unroll
        for (int o = 1; o < 64; o <<= 1) {
            int v = __shfl_up(incl, o, 64);
            if (lane >= o) incl += v;
        }
        if (lane == 63) wsum[w] = incl;
        __syncthreads();
        int wbase = 0;
        for (int k = 0; k < w; k++) wbase += wsum[k];
        int ex = wbase + incl - s;
        if (tid < 196) {
            lofs[2 * tid]     = ex;
            lofs[2 * tid + 1] = ex + c0;
        }
    }
    __syncthreads();
    for (int i = tid; i < NBUCKETS; i += 256) {
        int c = lh[i];
        if (c > 0) lbase[i] = atomicAdd(&bucketCursor[i], c);
        lh[i] = 0;
    }
    __syncthreads();
    #pragma unroll 4
    for (int k = 0; k < 32; k++) {
        int e = base + k * 256 + tid;
        if (e < N_EDGES) {
            int c = col[e];
            int bkt = c >> 8;
            int r = atomicAdd(&lh[bkt], 1);
            int slot = lofs[bkt] + r;
            stage[slot] = (row[e] << 8) | (c & 255);
            sbkt[slot] = (unsigned short)bkt;
        }
    }
    __syncthreads();
    int total = (base + EPB <= N_EDGES) ? EPB : (N_EDGES - base);
    for (int i = tid; i < total; i += 256) {
        int bkt = sbkt[i];
        bucketed[lbase[bkt] + (i - lofs[bkt])] = stage[i];
    }
}

// ---- Pass B: per-bucket fine sort + nodeinfo (degree-sorted) + xs prescale ----
__global__ void fine_sort_kernel(const int* __restrict__ bucketed,
                                 const int* __restrict__ bucketStart,
                                 const float* __restrict__ x,
                                 int* __restrict__ edge_src,
                                 int4* __restrict__ nodeinfo,
                                 __half2* __restrict__ xs) {
    __shared__ int fh[256];
    __shared__ int sfh[257];
    __shared__ int cur[256];
    __shared__ int dh[64];
    __shared__ int dbase[64];
    __shared__ float fdis[256];
    int b = blockIdx.x;
    int t = threadIdx.x;
    int s0 = bucketStart[b], s1 = bucketStart[b + 1];
    int nodeBase = b << 8;
    fh[t] = 0;
    if (t < 64) dh[t] = 0;
    __syncthreads();
    for (int j = s0 + t; j < s1; j += 256)
        atomicAdd(&fh[bucketed[j] & 255], 1);
    __syncthreads();
    if (t == 0) {
        int s = 0;
        for (int k = 0; k < 256; k++) { sfh[k] = s; s += fh[k]; }
        sfh[256] = s;
    }
    __syncthreads();
    int node = nodeBase + t;
    bool valid = (node < N_NODES);
    int d = fh[t];
    float dv = (valid && d > 0) ? rsqrtf((float)d) : 0.0f;
    cur[t] = sfh[t];
    fdis[t] = dv;
    int bin = 0, myrank = 0;
    if (valid) {
        bin = min(d, 63);
        myrank = atomicAdd(&dh[bin], 1);
    }
    __syncthreads();
    if (t == 0) {  // descending-degree exclusive scan (heavy nodes first)
        int s = 0;
        for (int k = 63; k >= 0; k--) { dbase[k] = s; s += dh[k]; }
    }
    __syncthreads();
    if (valid) {
        int pos = dbase[bin] + myrank;
        nodeinfo[nodeBase + pos] = make_int4(node, s0 + sfh[t], d, __float_as_int(dv));
    }
    // prescale: xs[node] = x[node] * dis (coalesced float2 reads)
    for (int i = t; i < 256 * 24; i += 256) {
        int ln = i / 24;
        int nd = nodeBase + ln;
        if (nd < N_NODES) {
            int ci = i - ln * 24;
            float dd = fdis[ln];
            float2 v = ((const float2*)x)[nd * 24 + ci];
            xs[nd * 24 + ci] = __floats2half2_rn(v.x * dd, v.y * dd);
        }
    }
    __syncthreads();
    for (int j = s0 + t; j < s1; j += 256) {
        int rc = bucketed[j];
        int p = atomicAdd(&cur[rc & 255], 1);
        edge_src[s0 + p] = rc >> 8;
    }
}

// ---- accumulate one 16 B fragment (4 half2 = 8 channels) into a[8] ----
__device__ __forceinline__ void acc8(float4 r, float (&a)[8]) {
    __half2 h0 = *(__half2*)&r.x, h1 = *(__half2*)&r.y;
    __half2 h2 = *(__half2*)&r.z, h3 = *(__half2*)&r.w;
    float2 f0 = __half22float2(h0), f1 = __half22float2(h1);
    float2 f2 = __half22float2(h2), f3 = __half22float2(h3);
    a[0] += f0.x; a[1] += f0.y; a[2] += f1.x; a[3] += f1.y;
    a[4] += f2.x; a[5] += f2.y; a[6] += f3.x; a[7] += f3.y;
}

// ---- gather round 1: 8-lane groups, lanes 0-5 active, dwordx4 per edge ----
// h1[i] = (sum_src xs[src]) * dis[i]^2   (folds round-2 source scaling)
__global__ void gather1_kernel(const __half2* __restrict__ xs,
                               const int* __restrict__ edge_src,
                               const int4* __restrict__ nodeinfo,
                               __half2* __restrict__ h1) {
    int g = blockIdx.x * 32 + (threadIdx.x >> 3);
    int lane = threadIdx.x & 7;
    if (lane >= 6) return;                 // no barriers in this kernel
    int4 ni = nodeinfo[g];
    int node = ni.x, s = ni.y, e = s + ni.z;
    float dv = __int_as_float(ni.w);
    float a[8] = {0, 0, 0, 0, 0, 0, 0, 0};
    int j = s;
    for (; j + 3 < e; j += 4) {
        int s0 = edge_src[j], s1 = edge_src[j + 1], s2 = edge_src[j + 2], s3 = edge_src[j + 3];
        float4 r0 = *(const float4*)(xs + s0 * ROW + lane * 4);
        float4 r1 = *(const float4*)(xs + s1 * ROW + lane * 4);
        float4 r2 = *(const float4*)(xs + s2 * ROW + lane * 4);
        float4 r3 = *(const float4*)(xs + s3 * ROW + lane * 4);
        acc8(r0, a); acc8(r1, a); acc8(r2, a); acc8(r3, a);
    }
    for (; j < e; ++j) {
        float4 r0 = *(const float4*)(xs + edge_src[j] * ROW + lane * 4);
        acc8(r0, a);
    }
    float sc = dv * dv;
    __half2 t0 = __floats2half2_rn(a[0] * sc, a[1] * sc);
    __half2 t1 = __floats2half2_rn(a[2] * sc, a[3] * sc);
    __half2 t2 = __floats2half2_rn(a[4] * sc, a[5] * sc);
    __half2 t3 = __floats2half2_rn(a[6] * sc, a[7] * sc);
    float4 w;
    w.x = *(float*)&t0; w.y = *(float*)&t1; w.z = *(float*)&t2; w.w = *(float*)&t3;
    *(float4*)(h1 + (size_t)node * ROW + lane * 4) = w;
}

// ---- gather round 2 fused with GEMM ----
__global__ void gather2_gemm_kernel(const __half2* __restrict__ h1,
                                    const int* __restrict__ edge_src,
                                    const int4* __restrict__ nodeinfo,
                                    const float* __restrict__ W,
                                    const float* __restrict__ bias,
                                    float* __restrict__ out) {
    __shared__ float sW[IN_CH * OUT_CH];
    __shared__ float sb[OUT_CH];
    __shared__ float sh[32][IN_CH + 2];

    for (int i = threadIdx.x; i < IN_CH * OUT_CH; i += 256) sW[i] = W[i];
    if (threadIdx.x < OUT_CH) sb[threadIdx.x] = bias[threadIdx.x];

    int nl = threadIdx.x >> 3;
    int lane = threadIdx.x & 7;
    int g = blockIdx.x * 32 + nl;
    int4 ni = nodeinfo[g];
    int node = ni.x, s = ni.y, e = s + ni.z;
    float dv = __int_as_float(ni.w);

    if (lane < 6) {
        float a[8] = {0, 0, 0, 0, 0, 0, 0, 0};
        int j = s;
        for (; j + 3 < e; j += 4) {
            int s0 = edge_src[j], s1 = edge_src[j + 1], s2 = edge_src[j + 2], s3 = edge_src[j + 3];
            float4 r0 = *(const float4*)(h1 + s0 * ROW + lane * 4);
            float4 r1 = *(const float4*)(h1 + s1 * ROW + lane * 4);
            float4 r2 = *(const float4*)(h1 + s2 * ROW + lane * 4);
            float4 r3 = *(const float4*)(h1 + s3 * ROW + lane * 4);
            acc8(r0, a); acc8(r1, a); acc8(r2, a); acc8(r3, a);
        }
        for (; j < e; ++j) {
            float4 r0 = *(const float4*)(h1 + edge_src[j] * ROW + lane * 4);
            acc8(r0, a);
        }
        #pragma unroll
        for (int k = 0; k < 8; k++) sh[nl][lane * 8 + k] = a[k] * dv;
    }
    __syncthreads();

    int j0 = lane * 8;
    float acc[8];
    #pragma unroll
    for (int i = 0; i < 8; i++) acc[i] = sb[j0 + i];
    for (int k = 0; k < IN_CH; k++) {
        float s0 = sh[nl][k];
        #pragma unroll
        for (int i = 0; i < 8; i++) acc[i] += s0 * sW[k * OUT_CH + j0 + i];
    }
    float4* o = (float4*)(out + (size_t)node * OUT_CH + j0);
    o[0] = make_float4(acc[0], acc[1], acc[2], acc[3]);
    o[1] = make_float4(acc[4], acc[5], acc[6], acc[7]);
}

extern "C" void kernel_launch(void* const* d_in, const int* in_sizes, int n_in,
                              void* d_out, int out_size, void* d_ws, size_t ws_size,
                              hipStream_t stream) {
    const float* x   = (const float*)d_in[0];
    const int*   ei  = (const int*)d_in[1];
    const float* W   = (const float*)d_in[2];
    const float* b   = (const float*)d_in[3];
    float* out = (float*)d_out;

    const int* row = ei;             // edge_index[0] (sources)
    const int* col = ei + N_EDGES;   // edge_index[1] (destinations)

    // ws layout (int offsets), ~33.7 MB total, no aliasing:
    int* ws_i = (int*)d_ws;
    int* bucketCount  = ws_i;                  // [392]
    int* bucketStart  = ws_i + 512;            // [393]
    int* bucketCursor = ws_i + 1024;           // [392]
    int4* nodeinfo    = (int4*)(ws_i + 2048);  // [100352] int4 (16B-aligned)
    int* edge_src     = ws_i + 403456;         // [1600000]
    int* bucketed     = ws_i + 2003456;        // [1600000] packed edges
    __half2* xs       = (__half2*)(ws_i + 3603456); // [2400000] half2 = 9.6 MB
    __half2* h1       = (__half2*)(ws_i + 6003456); // [2400000] half2 = 9.6 MB

    hipMemsetAsync(bucketCount, 0, NBUCKETS * sizeof(int), stream);

    bucket_hist_kernel<<<NBLK_EDGE, 256, 0, stream>>>(col, bucketCount);
    bucket_scan_kernel<<<1, 256, 0, stream>>>(bucketCount, bucketStart, bucketCursor);
    bucket_scatter_kernel<<<NBLK_EDGE, 256, 0, stream>>>(row, col, bucketCursor, bucketed);
    fine_sort_kernel<<<NBLK_BKT, 256, 0, stream>>>(bucketed, bucketStart, x,
                                                   edge_src, nodeinfo, xs);

    // 32 nodes per 256-thread block; 100000/32 = 3125 exactly
    gather1_kernel<<<N_NODES / 32, 256, 0, stream>>>(xs, edge_src, nodeinfo, h1);
    gather2_gemm_kernel<<<N_NODES / 32, 256, 0, stream>>>(h1, edge_src, nodeinfo, W, b, out);
}

// Round 10
// 232.045 us; speedup vs baseline: 1.0928x; 1.0928x over previous
//
#include <hip/hip_runtime.h>
#include <hip/hip_bf16.h>
#include <hip/hip_fp16.h>

// SGC: out = (D^-1/2 A D^-1/2)^2 x W + b.
// R9: fixed-capacity bucket regions (CAP=4608 per 256-node bucket) -> scatter
// reserves via cursor atomics directly; bucket_hist + bucket_scan kernels
// eliminated. Global descending-degree order restored (R6-best) via
// binscan+order. Gather fragment = R6-best (8 lanes x 12B, x4 unroll).
// fine_sort keeps fused xs prescale (R7).

#define N_NODES 100000
#define N_EDGES 1600000
#define IN_CH 48
#define OUT_CH 64
#define NBUCKETS 392             // bucket = col >> 8 (256 nodes each)
#define CAP 4608                 // slots per bucket region (mean 4082, +8.2 sigma)
#define EPB 8192                 // edges per scatter block
#define NBLK_EDGE 196            // ceil(1.6M / 8192)
#define NBLK_BKT 391             // buckets containing real nodes

// ---- init: bucket cursors at region bases; zero degree-bin totals ----
__global__ void init_kernel(int* __restrict__ bucketCursor, int* __restrict__ binTotal) {
    int t = threadIdx.x;
    if (t < NBUCKETS) bucketCursor[t] = t * CAP;
    if (t < 64) binTotal[t] = 0;
}

// ---- scatter packed edges into fixed bucket regions (LDS-staged) ----
__global__ void bucket_scatter_kernel(const int* __restrict__ row, const int* __restrict__ col,
                                      int* __restrict__ bucketCursor, int* __restrict__ edge_packed) {
    __shared__ int lh[NBUCKETS];
    __shared__ int lofs[NBUCKETS];
    __shared__ int lbase[NBUCKETS];
    __shared__ int stage[EPB];
    __shared__ unsigned short sbkt[EPB];
    __shared__ int wsum[4];
    int tid = threadIdx.x;
    int base = blockIdx.x * EPB;
    for (int i = tid; i < NBUCKETS; i += 256) lh[i] = 0;
    __syncthreads();
    #pragma unroll 4
    for (int k = 0; k < 32; k++) {
        int e = base + k * 256 + tid;
        if (e < N_EDGES) atomicAdd(&lh[col[e] >> 8], 1);
    }
    __syncthreads();
    // parallel exclusive scan of 392 counts (2 buckets/thread, 196 active)
    {
        int c0 = (tid < 196) ? lh[2 * tid] : 0;
        int c1 = (tid < 196) ? lh[2 * tid + 1] : 0;
        int s = c0 + c1;
        int incl = s;
        int lane = tid & 63, w = tid >> 6;
        #pragma unroll
        for (int o = 1; o < 64; o <<= 1) {
            int v = __shfl_up(incl, o, 64);
            if (lane >= o) incl += v;
        }
        if (lane == 63) wsum[w] = incl;
        __syncthreads();
        int wbase = 0;
        for (int k = 0; k < w; k++) wbase += wsum[k];
        int ex = wbase + incl - s;
        if (tid < 196) {
            lofs[2 * tid]     = ex;
            lofs[2 * tid + 1] = ex + c0;
        }
    }
    __syncthreads();
    for (int i = tid; i < NBUCKETS; i += 256) {
        int c = lh[i];
        if (c > 0) lbase[i] = atomicAdd(&bucketCursor[i], c);
        lh[i] = 0;
    }
    __syncthreads();
    // stage edges packed (row<<8 | col&255)
    #pragma unroll 4
    for (int k = 0; k < 32; k++) {
        int e = base + k * 256 + tid;
        if (e < N_EDGES) {
            int c = col[e];
            int bkt = c >> 8;
            int r = atomicAdd(&lh[bkt], 1);
            int slot = lofs[bkt] + r;
            stage[slot] = (row[e] << 8) | (c & 255);
            sbkt[slot] = (unsigned short)bkt;
        }
    }
    __syncthreads();
    int total = (base + EPB <= N_EDGES) ? EPB : (N_EDGES - base);
    for (int i = tid; i < total; i += 256) {
        int bkt = sbkt[i];
        int dst = lbase[bkt] + (i - lofs[bkt]);
        if (dst < (bkt + 1) * CAP)           // overflow guard (P ~ 5e-14)
            edge_packed[dst] = stage[i];
    }
}

// ---- per-bucket fine sort -> edge_src/deg/start/dis + bin hist + xs prescale ----
__global__ void fine_sort_kernel(const int* __restrict__ edge_packed,
                                 const int* __restrict__ bucketCursor,
                                 const float* __restrict__ x,
                                 int* __restrict__ edge_src,
                                 int* __restrict__ deg, int* __restrict__ start,
                                 float* __restrict__ dis, int* __restrict__ binTotal,
                                 __half2* __restrict__ xs) {
    __shared__ int fh[256];
    __shared__ int sfh[257];
    __shared__ int cur[256];
    __shared__ int bh[64];
    __shared__ float fdis[256];
    int b = blockIdx.x;
    int t = threadIdx.x;
    int s0 = b * CAP;
    int s1 = min(bucketCursor[b], (b + 1) * CAP);
    int nodeBase = b << 8;
    fh[t] = 0;
    if (t < 64) bh[t] = 0;
    __syncthreads();
    for (int j = s0 + t; j < s1; j += 256)
        atomicAdd(&fh[edge_packed[j] & 255], 1);
    __syncthreads();
    if (t == 0) {
        int s = 0;
        for (int k = 0; k < 256; k++) { sfh[k] = s; s += fh[k]; }
        sfh[256] = s;
    }
    __syncthreads();
    int node = nodeBase + t;
    bool valid = (node < N_NODES);
    int d = fh[t];
    float dv = (valid && d > 0) ? rsqrtf((float)d) : 0.0f;
    cur[t] = sfh[t];
    fdis[t] = dv;
    if (valid) {
        deg[node] = d;
        start[node] = s0 + sfh[t];
        dis[node] = dv;
        atomicAdd(&bh[min(d, 63)], 1);
    }
    __syncthreads();
    // prescale: xs[node] = x[node] * dis (coalesced float2 reads)
    for (int i = t; i < 256 * 24; i += 256) {
        int ln = i / 24;
        int nd = nodeBase + ln;
        if (nd < N_NODES) {
            int ci = i - ln * 24;
            float dd = fdis[ln];
            float2 v = ((const float2*)x)[nd * 24 + ci];
            xs[nd * 24 + ci] = __floats2half2_rn(v.x * dd, v.y * dd);
        }
    }
    // permute into per-node runs
    for (int j = s0 + t; j < s1; j += 256) {
        int rc = edge_packed[j];
        int p = atomicAdd(&cur[rc & 255], 1);
        edge_src[s0 + p] = rc >> 8;
    }
    __syncthreads();
    if (t < 64 && bh[t]) atomicAdd(&binTotal[t], bh[t]);
}

// ---- exclusive scan of degree bins, DESCENDING (heavy nodes first) ----
__global__ void binscan_kernel(const int* __restrict__ binTotal, int* __restrict__ binCursor) {
    if (threadIdx.x == 0) {
        int s = 0;
        for (int k = 63; k >= 0; k--) { binCursor[k] = s; s += binTotal[k]; }
    }
}

// ---- build globally degree-sorted nodeinfo: {node, start, deg, dis} ----
__global__ void order_kernel(const int* __restrict__ deg, const int* __restrict__ start,
                             const float* __restrict__ dis, int* __restrict__ binCursor,
                             int4* __restrict__ nodeinfo, int n) {
    __shared__ int lhist[64];
    __shared__ int lbase[64];
    int i = blockIdx.x * 256 + threadIdx.x;
    if (threadIdx.x < 64) lhist[threadIdx.x] = 0;
    __syncthreads();
    int bin = 0, myrank = 0;
    if (i < n) {
        bin = min(deg[i], 63);
        myrank = atomicAdd(&lhist[bin], 1);
    }
    __syncthreads();
    if (threadIdx.x < 64 && lhist[threadIdx.x] > 0)
        lbase[threadIdx.x] = atomicAdd(&binCursor[threadIdx.x], lhist[threadIdx.x]);
    __syncthreads();
    if (i < n)
        nodeinfo[lbase[bin] + myrank] = make_int4(i, start[i], deg[i], __float_as_int(dis[i]));
}

// Per-lane row chunk: 3 consecutive half2 at row*24 + lane*3 (12 B contiguous).
#define LOAD3(p, v0, v1, v2) { v0 = (p)[0]; v1 = (p)[1]; v2 = (p)[2]; }
#define ACC6(v0, v1, v2) { \
    float2 u0 = __half22float2(v0), u1 = __half22float2(v1), u2 = __half22float2(v2); \
    a0 += u0.x; a1 += u0.y; a2 += u1.x; a3 += u1.y; a4 += u2.x; a5 += u2.y; }
#define ACC6B(v0, v1, v2) { \
    float2 u0 = __half22float2(v0), u1 = __half22float2(v1), u2 = __half22float2(v2); \
    b0 += u0.x; b1 += u0.y; b2 += u1.x; b3 += u1.y; b4 += u2.x; b5 += u2.y; }

// ---- gather round 1: 8 lanes/node, x4 unroll, dual accumulators ----
// h1[i] = (sum_src xs[src]) * dis[i]^2   (folds round-2 source scaling)
__global__ void gather1_kernel(const __half2* __restrict__ xs,
                               const int* __restrict__ edge_src,
                               const int4* __restrict__ nodeinfo,
                               __half2* __restrict__ h1) {
    int g = blockIdx.x * 32 + (threadIdx.x >> 3);
    int lane = threadIdx.x & 7;
    int4 ni = nodeinfo[g];
    int node = ni.x, s = ni.y, e = s + ni.z;
    float dv = __int_as_float(ni.w);
    float a0 = 0, a1 = 0, a2 = 0, a3 = 0, a4 = 0, a5 = 0;
    float b0 = 0, b1 = 0, b2 = 0, b3 = 0, b4 = 0, b5 = 0;
    int j = s;
    for (; j + 3 < e; j += 4) {
        int s0 = edge_src[j], s1 = edge_src[j + 1], s2 = edge_src[j + 2], s3 = edge_src[j + 3];
        const __half2* p0 = xs + s0 * 24 + lane * 3;
        const __half2* p1 = xs + s1 * 24 + lane * 3;
        const __half2* p2 = xs + s2 * 24 + lane * 3;
        const __half2* p3 = xs + s3 * 24 + lane * 3;
        __half2 v00,v01,v02, v10,v11,v12, v20,v21,v22, v30,v31,v32;
        LOAD3(p0, v00, v01, v02); LOAD3(p1, v10, v11, v12);
        LOAD3(p2, v20, v21, v22); LOAD3(p3, v30, v31, v32);
        ACC6(v00, v01, v02); ACC6B(v10, v11, v12);
        ACC6(v20, v21, v22); ACC6B(v30, v31, v32);
    }
    for (; j < e; ++j) {
        const __half2* p0 = xs + edge_src[j] * 24 + lane * 3;
        __half2 v00, v01, v02;
        LOAD3(p0, v00, v01, v02);
        ACC6(v00, v01, v02);
    }
    a0 += b0; a1 += b1; a2 += b2; a3 += b3; a4 += b4; a5 += b5;
    float sc = dv * dv;
    __half2* q = h1 + node * 24 + lane * 3;
    q[0] = __floats2half2_rn(a0 * sc, a1 * sc);
    q[1] = __floats2half2_rn(a2 * sc, a3 * sc);
    q[2] = __floats2half2_rn(a4 * sc, a5 * sc);
}

// ---- gather round 2 fused with GEMM ----
__global__ void gather2_gemm_kernel(const __half2* __restrict__ h1,
                                    const int* __restrict__ edge_src,
                                    const int4* __restrict__ nodeinfo,
                                    const float* __restrict__ W,
                                    const float* __restrict__ bias,
                                    float* __restrict__ out) {
    __shared__ float sW[IN_CH * OUT_CH];
    __shared__ float sb[OUT_CH];
    __shared__ float sh[32][IN_CH + 1];

    for (int i = threadIdx.x; i < IN_CH * OUT_CH; i += 256) sW[i] = W[i];
    if (threadIdx.x < OUT_CH) sb[threadIdx.x] = bias[threadIdx.x];

    int nl = threadIdx.x >> 3;
    int lane = threadIdx.x & 7;
    int g = blockIdx.x * 32 + nl;
    int4 ni = nodeinfo[g];
    int node = ni.x, s = ni.y, e = s + ni.z;
    float dv = __int_as_float(ni.w);

    float a0 = 0, a1 = 0, a2 = 0, a3 = 0, a4 = 0, a5 = 0;
    float b0 = 0, b1 = 0, b2 = 0, b3 = 0, b4 = 0, b5 = 0;
    int j = s;
    for (; j + 3 < e; j += 4) {
        int s0 = edge_src[j], s1 = edge_src[j + 1], s2 = edge_src[j + 2], s3 = edge_src[j + 3];
        const __half2* p0 = h1 + s0 * 24 + lane * 3;
        const __half2* p1 = h1 + s1 * 24 + lane * 3;
        const __half2* p2 = h1 + s2 * 24 + lane * 3;
        const __half2* p3 = h1 + s3 * 24 + lane * 3;
        __half2 v00,v01,v02, v10,v11,v12, v20,v21,v22, v30,v31,v32;
        LOAD3(p0, v00, v01, v02); LOAD3(p1, v10, v11, v12);
        LOAD3(p2, v20, v21, v22); LOAD3(p3, v30, v31, v32);
        ACC6(v00, v01, v02); ACC6B(v10, v11, v12);
        ACC6(v20, v21, v22); ACC6B(v30, v31, v32);
    }
    for (; j < e; ++j) {
        const __half2* p0 = h1 + edge_src[j] * 24 + lane * 3;
        __half2 v00, v01, v02;
        LOAD3(p0, v00, v01, v02);
        ACC6(v00, v01, v02);
    }
    a0 += b0; a1 += b1; a2 += b2; a3 += b3; a4 += b4; a5 += b5;
    int c0 = 6 * lane;
    sh[nl][c0 + 0] = a0 * dv;
    sh[nl][c0 + 1] = a1 * dv;
    sh[nl][c0 + 2] = a2 * dv;
    sh[nl][c0 + 3] = a3 * dv;
    sh[nl][c0 + 4] = a4 * dv;
    sh[nl][c0 + 5] = a5 * dv;
    __syncthreads();

    int j0 = lane * 8;
    float acc[8];
    #pragma unroll
    for (int i = 0; i < 8; i++) acc[i] = sb[j0 + i];
    for (int k = 0; k < IN_CH; k++) {
        float s0 = sh[nl][k];
        #pragma unroll
        for (int i = 0; i < 8; i++) acc[i] += s0 * sW[k * OUT_CH + j0 + i];
    }
    float4* o = (float4*)(out + (size_t)node * OUT_CH + j0);
    o[0] = make_float4(acc[0], acc[1], acc[2], acc[3]);
    o[1] = make_float4(acc[4], acc[5], acc[6], acc[7]);
}

extern "C" void kernel_launch(void* const* d_in, const int* in_sizes, int n_in,
                              void* d_out, int out_size, void* d_ws, size_t ws_size,
                              hipStream_t stream) {
    const float* x   = (const float*)d_in[0];
    const int*   ei  = (const int*)d_in[1];
    const float* W   = (const float*)d_in[2];
    const float* b   = (const float*)d_in[3];
    float* out = (float*)d_out;

    const int* row = ei;             // edge_index[0] (sources)
    const int* col = ei + N_EDGES;   // edge_index[1] (destinations)

    // ws layout (int offsets), ~36.5 MB total:
    int* ws_i = (int*)d_ws;
    int* bucketCursor = ws_i;                       // [512]
    int* binTotal     = ws_i + 512;                 // [64]
    int* binCursor    = ws_i + 576;                 // [64]
    int* deg          = ws_i + 1024;                // [100352]
    int* start        = ws_i + 101376;              // [100352]
    float* dis        = (float*)(ws_i + 201728);    // [100352]
    int4* nodeinfo    = (int4*)(ws_i + 302080);     // [100352] int4 (16B-aligned)
    int* edge_packed  = ws_i + 703488;              // [392*4608 = 1806336]
    int* edge_src     = ws_i + 2509824;             // [1806336] (holes between buckets)
    __half2* xs       = (__half2*)(ws_i + 4316160); // [2400000] half2 = 9.6 MB
    __half2* h1       = (__half2*)(ws_i + 6716160); // [2400000] half2 = 9.6 MB

    init_kernel<<<1, 512, 0, stream>>>(bucketCursor, binTotal);
    bucket_scatter_kernel<<<NBLK_EDGE, 256, 0, stream>>>(row, col, bucketCursor, edge_packed);
    fine_sort_kernel<<<NBLK_BKT, 256, 0, stream>>>(edge_packed, bucketCursor, x,
                                                   edge_src, deg, start, dis, binTotal, xs);
    binscan_kernel<<<1, 64, 0, stream>>>(binTotal, binCursor);
    order_kernel<<<(N_NODES + 255) / 256, 256, 0, stream>>>(deg, start, dis, binCursor,
                                                            nodeinfo, N_NODES);

    // 32 nodes per 256-thread block; 100000/32 = 3125 exactly
    gather1_kernel<<<N_NODES / 32, 256, 0, stream>>>(xs, edge_src, nodeinfo, h1);
    gather2_gemm_kernel<<<N_NODES / 32, 256, 0, stream>>>(h1, edge_src, nodeinfo, W, b, out);
}